// Round 6
// baseline (275.589 us; speedup 1.0000x reference)
//
#include <hip/hip_runtime.h>
#include <hip/hip_cooperative_groups.h>

namespace cg = cooperative_groups;

#define B_ 256
#define N_IN 1152
#define N_OUT 10
#define OJ 160                     // N_OUT * D_OUT
#define SN (B_*OJ)                 // 40960
#define LOG2E 1.44269504088896340736f
#define SGN 16                     // n supergroups (partials)
#define NPS (N_IN/SGN)             // 72 n per block
#define NTHR 512
#define NBLK 256                   // 16 bg x 16 sg
#define GSZ (NBLK*NTHR)            // 131072
#define NW_ELEMS (N_IN*N_OUT*16)   // 184320 rows of 8 (W)
#define NX_ELEMS (B_*N_IN)         // 294912 rows of 8 (x)
#define NTILES ((N_IN/16)*(B_/16)) // 1152 x-transpose tiles

typedef __attribute__((ext_vector_type(8))) short bf16x8;
typedef __attribute__((ext_vector_type(4))) float f32x4;

// ---- bf16 split helpers (RNE) ----
__device__ __forceinline__ unsigned short f2bf(float f) {
  unsigned u = __float_as_uint(f);
  u += 0x7fffu + ((u >> 16) & 1u);
  return (unsigned short)(u >> 16);
}
__device__ __forceinline__ float bf2f(unsigned short s) {
  return __uint_as_float(((unsigned)s) << 16);
}
__device__ __forceinline__ void split8(const float* p, bf16x8& vh, bf16x8& vl) {
  const float4 a = *(const float4*)p;
  const float4 b = *(const float4*)(p + 4);
  const float w[8] = {a.x,a.y,a.z,a.w,b.x,b.y,b.z,b.w};
#pragma unroll
  for (int e=0;e<8;e++){
    unsigned short hh = f2bf(w[e]);
    vh[e] = (short)hh;
    vl[e] = (short)f2bf(w[e] - bf2f(hh));
  }
}

// ---- DPP rotate-reduce over a 16-lane row ----
template<int CTRL>
__device__ __forceinline__ float dpp_add(float xx) {
  int y = __builtin_amdgcn_mov_dpp(__float_as_int(xx), CTRL, 0xF, 0xF, false);
  return xx + __int_as_float(y);
}
__device__ __forceinline__ float row_sum16(float xx) {
  xx = dpp_add<0x128>(xx); xx = dpp_add<0x124>(xx);
  xx = dpp_add<0x122>(xx); xx = dpp_add<0x121>(xx);
  return xx;
}
__device__ __forceinline__ float squash_elem(float t) {
  const float sq = row_sum16(t * t);
  return t * (sq / (1.f + sq)) * rsqrtf(sq + 1e-8f);
}

// K-chunk trick: one 16x16x32 MFMA; lane's K-chunk c=l>>4 pulls A from
// [WH,WL,WH,WL] and B from [XH,XH,XL,XL] => exact (Wh+Wl)(xh+xl).
// C layout: col=lane&15=b, row=c*4+e=j.
template<bool UNIFORM>
__device__ __forceinline__ void pass_core(const short* __restrict__ Abase,
                                          const short* __restrict__ Bbase,
                                          const float* __restrict__ veff,
                                          float* __restrict__ P,
                                          float (*red)[2560],
                                          int sg, int b0, int n0,
                                          int w, int bb, int c) {
  const f32x4 zz = {0.f,0.f,0.f,0.f};
  f32x4 acc[N_OUT], vj[N_OUT];
#pragma unroll
  for (int o=0;o<N_OUT;o++) acc[o] = zz;
  if (!UNIFORM) {
    const float* vp = &veff[(size_t)(b0+bb)*OJ + c*4];
#pragma unroll
    for (int o=0;o<N_OUT;o++) vj[o] = *(const f32x4*)&vp[o*16];
  }
  for (int k=0;k<9;k++) {                 // wave w covers n = n0+w+8k, k=0..8
    const int n = n0 + w + 8*k;
    const bf16x8 bfrag = *(const bf16x8*)&Bbase[((size_t)n*B_ + b0 + bb)*8];
    const short* Ap = &Abase[(size_t)n*1280 + bb*8];
    if (UNIFORM) {
#pragma unroll
      for (int o=0;o<N_OUT;o++) {
        const bf16x8 afrag = *(const bf16x8*)&Ap[o*128];
        acc[o] = __builtin_amdgcn_mfma_f32_16x16x32_bf16(afrag, bfrag, acc[o], 0,0,0);
      }
    } else {
      f32x4 u[N_OUT];
#pragma unroll
      for (int o=0;o<N_OUT;o++) {
        const bf16x8 afrag = *(const bf16x8*)&Ap[o*128];
        u[o] = __builtin_amdgcn_mfma_f32_16x16x32_bf16(afrag, bfrag, zz, 0,0,0);
      }
      float ez[N_OUT], Z = 0.f;
#pragma unroll
      for (int o=0;o<N_OUT;o++) {
        float t = u[o][0]*vj[o][0] + u[o][1]*vj[o][1]
                + u[o][2]*vj[o][2] + u[o][3]*vj[o][3];
        t += __shfl_xor(t, 16);
        t += __shfl_xor(t, 32);
        ez[o] = exp2f(t);                 // veff stored in log2 domain
        Z += ez[o];
      }
      const float invZ = 1.f / Z;
#pragma unroll
      for (int o=0;o<N_OUT;o++) acc[o] += (ez[o]*invZ) * u[o];
    }
  }
  // 8-wave LDS tree -> wave 0 -> P slice
  const int slot4 = (bb*4 + c)*4;
  if (w >= 4) {
#pragma unroll
    for (int o=0;o<N_OUT;o++) *(f32x4*)&red[w-4][o*256 + slot4] = acc[o];
  }
  __syncthreads();
  if (w < 4) {
#pragma unroll
    for (int o=0;o<N_OUT;o++) acc[o] += *(const f32x4*)&red[w][o*256 + slot4];
  }
  __syncthreads();
  if (w == 2 || w == 3) {
#pragma unroll
    for (int o=0;o<N_OUT;o++) *(f32x4*)&red[w-2][o*256 + slot4] = acc[o];
  }
  __syncthreads();
  if (w < 2) {
#pragma unroll
    for (int o=0;o<N_OUT;o++) acc[o] += *(const f32x4*)&red[w][o*256 + slot4];
  }
  __syncthreads();
  if (w == 1) {
#pragma unroll
    for (int o=0;o<N_OUT;o++) *(f32x4*)&red[0][o*256 + slot4] = acc[o];
  }
  __syncthreads();
  if (w == 0) {
    float* Pp = &P[(size_t)sg*SN + (size_t)(b0+bb)*OJ + c*4];
#pragma unroll
    for (int o=0;o<N_OUT;o++) {
      acc[o] += *(const f32x4*)&red[0][o*256 + slot4];
      *(f32x4*)&Pp[o*16] = acc[o];
    }
  }
  __syncthreads();
}

// =================== single cooperative mega-kernel ===================
__global__ __launch_bounds__(NTHR) void caps_mega(
    const float* __restrict__ W, const float* __restrict__ x,
    short* __restrict__ WH, short* __restrict__ WL,
    short* __restrict__ XH, short* __restrict__ XL,
    float* __restrict__ P, float* __restrict__ v1buf,
    float* __restrict__ v12buf, float* __restrict__ out) {
  cg::grid_group grid = cg::this_grid();
  __shared__ float red[4][2560];               // 40 KB, aliased by pack tiles
  const int tid = threadIdx.x;
  const int bid = blockIdx.x;
  const int gtid = bid*NTHR + tid;

  // ---- Phase A: pack W (grid-stride) + x (LDS-transposed 16x16 tiles) ----
  for (int t = gtid; t < NW_ELEMS; t += GSZ) {
    bf16x8 vh, vl;
    split8(W + (size_t)t*8, vh, vl);
    ((bf16x8*)WH)[t] = vh; ((bf16x8*)WL)[t] = vl;
  }
  {
    const int unit = tid >> 8, utid = tid & 255;     // 2 tile-units per block
    bf16x8* TH = (bf16x8*)red + unit*544;
    bf16x8* TL = TH + 272;
    for (int iter = 0; iter < 3; ++iter) {
      const int tile = iter*(NBLK*2) + bid*2 + unit;
      const bool ok = tile < NTILES;
      int nt = 0, bt = 0;
      if (ok) {
        nt = tile >> 4; bt = tile & 15;
        const int nn = utid & 15, bb = utid >> 4;    // n fastest: coalesced reads
        bf16x8 vh, vl;
        split8(x + ((size_t)(bt*16+bb)*N_IN + nt*16+nn)*8, vh, vl);
        TH[nn*17 + bb] = vh; TL[nn*17 + bb] = vl;
      }
      __syncthreads();
      if (ok) {
        const int bb2 = utid & 15, nn2 = utid >> 4;  // b fastest: coalesced writes
        const size_t o = (size_t)(nt*16+nn2)*B_ + bt*16 + bb2;
        ((bf16x8*)XH)[o] = TH[nn2*17 + bb2];
        ((bf16x8*)XL)[o] = TL[nn2*17 + bb2];
      }
      __syncthreads();
    }
  }
  grid.sync();

  const int sg = bid >> 4, bg = bid & 15;
  const int b0 = bg*16, n0 = sg*NPS;
  const int w = tid >> 6, l = tid & 63;
  const int bb = l & 15, c = l >> 4;
  const short* Abase = (c & 1)  ? WL : WH;
  const short* Bbase = (c >> 1) ? XL : XH;

  // ---- Phase B: pass 1 (uniform coupling) ----
  pass_core<true>(Abase, Bbase, nullptr, P, red, sg, b0, n0, w, bb, c);
  grid.sync();
  // ---- Phase C: finish 1 -> v1 (log2-scaled) ----
  if (gtid < SN) {
    float s = 0.f;
#pragma unroll
    for (int g=0; g<SGN; ++g) s += P[(size_t)g*SN + gtid];
    v1buf[gtid] = squash_elem(0.1f*s) * LOG2E;
  }
  grid.sync();
  // ---- Phase D: pass 2 ----
  pass_core<false>(Abase, Bbase, v1buf, P, red, sg, b0, n0, w, bb, c);
  grid.sync();
  // ---- Phase E: finish 2 -> v12 = v1 + squash(s2) (log2-scaled) ----
  if (gtid < SN) {
    float s = 0.f;
#pragma unroll
    for (int g=0; g<SGN; ++g) s += P[(size_t)g*SN + gtid];
    v12buf[gtid] = v1buf[gtid] + squash_elem(s) * LOG2E;
  }
  grid.sync();
  // ---- Phase F: pass 3 ----
  pass_core<false>(Abase, Bbase, v12buf, P, red, sg, b0, n0, w, bb, c);
  grid.sync();
  // ---- Phase G: finish 3 -> out (natural scale) ----
  if (gtid < SN) {
    float s = 0.f;
#pragma unroll
    for (int g=0; g<SGN; ++g) s += P[(size_t)g*SN + gtid];
    out[gtid] = squash_elem(s);
  }
}

// =================== fallback: multi-kernel path (same ws layout) ===================
#define NWB (NW_ELEMS/256)
__global__ __launch_bounds__(256) void fb_pack(const float* __restrict__ W,
                                               const float* __restrict__ x,
                                               short* __restrict__ WH, short* __restrict__ WL,
                                               short* __restrict__ XH, short* __restrict__ XL) {
  const int bid = blockIdx.x, tid = threadIdx.x;
  if (bid < NWB) {
    const int t = bid*256 + tid;
    bf16x8 vh, vl; split8(W + (size_t)t*8, vh, vl);
    ((bf16x8*)WH)[t] = vh; ((bf16x8*)WL)[t] = vl;
  } else {
    __shared__ bf16x8 TH[16*17], TL[16*17];
    const int tile = bid - NWB;
    const int nt = tile >> 4, bt = tile & 15;
    const int nn = tid & 15, bb = tid >> 4;
    bf16x8 vh, vl;
    split8(x + ((size_t)(bt*16+bb)*N_IN + nt*16+nn)*8, vh, vl);
    TH[nn*17 + bb] = vh; TL[nn*17 + bb] = vl;
    __syncthreads();
    const int bb2 = tid & 15, nn2 = tid >> 4;
    const size_t o = (size_t)(nt*16+nn2)*B_ + bt*16 + bb2;
    ((bf16x8*)XH)[o] = TH[nn2*17 + bb2];
    ((bf16x8*)XL)[o] = TL[nn2*17 + bb2];
  }
}

template<bool UNIFORM>
__global__ __launch_bounds__(256) void fb_pass(const short* __restrict__ WH,
                                               const short* __restrict__ WL,
                                               const short* __restrict__ XH,
                                               const short* __restrict__ XL,
                                               const float* __restrict__ veff,
                                               float* __restrict__ P) {
  __shared__ f32x4 red[3*640];
  const int tid = threadIdx.x, w = tid >> 6, l = tid & 63;
  const int bb = l & 15, c = l >> 4;
  const int sg = blockIdx.x, bg = blockIdx.y;
  const int b0 = bg*16;
  const int n0 = sg*NPS + w*18;
  const short* Abase = (c & 1)  ? WL : WH;
  const short* Bbase = (c >> 1) ? XL : XH;

  const f32x4 zz = {0.f,0.f,0.f,0.f};
  f32x4 acc[N_OUT], vj[N_OUT];
#pragma unroll
  for (int o=0;o<N_OUT;o++) acc[o] = zz;
  if (!UNIFORM) {
    const float* vp = &veff[(size_t)(b0+bb)*OJ + c*4];
#pragma unroll
    for (int o=0;o<N_OUT;o++) vj[o] = *(const f32x4*)&vp[o*16];
  }
  for (int nn=0; nn<18; ++nn) {
    const int n = n0 + nn;
    const bf16x8 bfrag = *(const bf16x8*)&Bbase[((size_t)n*B_ + b0 + bb)*8];
    const short* Ap = &Abase[(size_t)n*1280 + bb*8];
    if (UNIFORM) {
#pragma unroll
      for (int o=0;o<N_OUT;o++) {
        const bf16x8 afrag = *(const bf16x8*)&Ap[o*128];
        acc[o] = __builtin_amdgcn_mfma_f32_16x16x32_bf16(afrag, bfrag, acc[o], 0,0,0);
      }
    } else {
      f32x4 u[N_OUT];
#pragma unroll
      for (int o=0;o<N_OUT;o++) {
        const bf16x8 afrag = *(const bf16x8*)&Ap[o*128];
        u[o] = __builtin_amdgcn_mfma_f32_16x16x32_bf16(afrag, bfrag, zz, 0,0,0);
      }
      float ez[N_OUT], Z = 0.f;
#pragma unroll
      for (int o=0;o<N_OUT;o++) {
        float t = u[o][0]*vj[o][0] + u[o][1]*vj[o][1]
                + u[o][2]*vj[o][2] + u[o][3]*vj[o][3];
        t += __shfl_xor(t, 16);
        t += __shfl_xor(t, 32);
        ez[o] = exp2f(t);
        Z += ez[o];
      }
      const float invZ = 1.f / Z;
#pragma unroll
      for (int o=0;o<N_OUT;o++) acc[o] += (ez[o]*invZ)*u[o];
    }
  }
  const int slot = bb*4 + c;
  if (w) {
    f32x4* r = &red[(w-1)*640];
#pragma unroll
    for (int o=0;o<N_OUT;o++) r[o*64 + slot] = acc[o];
  }
  __syncthreads();
  if (!w) {
#pragma unroll
    for (int o=0;o<N_OUT;o++)
      acc[o] += red[o*64+slot] + red[640+o*64+slot] + red[1280+o*64+slot];
    float* Pp = &P[(size_t)sg*SN + (size_t)(b0+bb)*OJ + c*4];
#pragma unroll
    for (int o=0;o<N_OUT;o++) *(f32x4*)&Pp[o*16] = acc[o];
  }
}

__global__ __launch_bounds__(256) void fb_finish(const float* __restrict__ P, float scale,
                                                 const float* __restrict__ vprev,
                                                 float* __restrict__ vout, float lscale) {
  const int idx = blockIdx.x*256 + threadIdx.x;
  float t = 0.f;
#pragma unroll
  for (int g=0; g<SGN; ++g) t += P[(size_t)g*SN + idx];
  t *= scale;
  float v = squash_elem(t) * lscale;
  if (vprev != nullptr) v += vprev[idx];
  vout[idx] = v;
}

extern "C" void kernel_launch(void* const* d_in, const int* in_sizes, int n_in,
                              void* d_out, int out_size, void* d_ws, size_t ws_size,
                              hipStream_t stream) {
  const float* x = (const float*)d_in[0];   // (256,1152,8)
  const float* W = (const float*)d_in[1];   // (1,1152,10,16,8)
  float* out = (float*)d_out;               // (256,10,16)

  float* P   = (float*)d_ws;                // SGN*SN floats = 2.6 MB
  float* v1  = P  + (size_t)SGN*SN;         // stored * log2e
  float* v12 = v1 + SN;                     // stored * log2e
  short* WH = (short*)(v12 + SN);
  short* WL = WH + (size_t)NW_ELEMS*8;
  short* XH = WL + (size_t)NW_ELEMS*8;
  short* XL = XH + (size_t)NX_ELEMS*8;      // total ws ~= 18.3 MB

  void* args[] = {(void*)&W, (void*)&x, (void*)&WH, (void*)&WL, (void*)&XH,
                  (void*)&XL, (void*)&P, (void*)&v1, (void*)&v12, (void*)&out};
  hipError_t err = hipLaunchCooperativeKernel((const void*)caps_mega,
                                              dim3(NBLK), dim3(NTHR), args, 0, stream);
  if (err != hipSuccess) {
    // fallback: proven multi-kernel pipeline, same ws layout (16 partial groups)
    fb_pack<<<NWB + NTILES, 256, 0, stream>>>(W, x, WH, WL, XH, XL);
    const dim3 pg(SGN, 16), pb(256);
    fb_pass<true ><<<pg, pb, 0, stream>>>(WH, WL, XH, XL, nullptr, P);
    fb_finish<<<SN/256, 256, 0, stream>>>(P, 0.1f, nullptr, v1, LOG2E);
    fb_pass<false><<<pg, pb, 0, stream>>>(WH, WL, XH, XL, v1, P);
    fb_finish<<<SN/256, 256, 0, stream>>>(P, 1.0f, v1, v12, LOG2E);
    fb_pass<false><<<pg, pb, 0, stream>>>(WH, WL, XH, XL, v12, P);
    fb_finish<<<SN/256, 256, 0, stream>>>(P, 1.0f, nullptr, out, 1.0f);
  }
}